// Round 4
// baseline (452.159 us; speedup 1.0000x reference)
//
#include <hip/hip_runtime.h>
#include <hip/hip_bf16.h>

typedef unsigned short u16;
typedef __attribute__((ext_vector_type(8))) short short8;
typedef __attribute__((ext_vector_type(4))) float f32x4;

// async global->LDS 16B per lane; LDS dest = wave-uniform base + lane*16
#define ASYNC16(ldsp, gp) __builtin_amdgcn_global_load_lds( \
    (const __attribute__((address_space(1))) unsigned int*)(gp), \
    (__attribute__((address_space(3))) unsigned int*)(ldsp), 16, 0, 0)

// ---------- helpers ----------
__device__ __forceinline__ float bf2f(u16 u){
  union { unsigned int i; float f; } v; v.i = ((unsigned int)u) << 16; return v.f;
}
__device__ __forceinline__ u16 f2bf(float f){
  union { float f; unsigned int i; } v; v.f = f;
  unsigned int x = v.i;
  return (u16)((x + 0x7fffu + ((x >> 16) & 1u)) >> 16);
}
__device__ __forceinline__ float gelu_exact(float x){
  return 0.5f * x * (1.0f + erff(x * 0.70710678118654752440f));
}

// B=32 N=320 C=768 H=12 S=256 T=64 hd=64; ALL I/O fp32.

// ---------- convert fp32 -> bf16 ----------
__global__ void k_cvt(const float* __restrict__ src, u16* __restrict__ dst, int n4){
  int i = blockIdx.x*256 + threadIdx.x;
  if (i < n4){
    float4 v = ((const float4*)src)[i];
    ushort4 p; p.x = f2bf(v.x); p.y = f2bf(v.y); p.z = f2bf(v.z); p.w = f2bf(v.w);
    ((ushort4*)dst)[i] = p;
  }
}

// ---------- fused: tgt_rep mean-pool + tgt-half of dp1 (per batch) ----------
__global__ void k_tgtdp(const float* __restrict__ x, const float* __restrict__ tmask,
                        const float* __restrict__ w1, const float* __restrict__ b1,
                        float* __restrict__ tgtdp){
  __shared__ float tg[768];
  int b = blockIdx.x;
  for (int c = threadIdx.x; c < 768; c += 384){
    float s = 0.f;
    for (int t2 = 0; t2 < 64; ++t2)
      s += x[(size_t)(b*320 + t2)*768 + c] * tmask[b*64 + t2];
    tg[c] = s * (1.0f/64.0f);
  }
  __syncthreads();
  int o = threadIdx.x;   // 384
  float s = b1[o];
  const float* wr = w1 + (size_t)o*1536 + 768;
  for (int c = 0; c < 768; ++c) s += tg[c] * wr[c];
  tgtdp[b*384 + o] = s;
}

// ---------- mlp1 fp32 SGEMM 128x64 tile, 8x4 per thread (decision path) ----------
// h1[8192,384] = gelu( x[search rows][768] @ dp1_w[:, :768]^T + tgtdp )
__global__ __launch_bounds__(256)
void k_mlp1(const float* __restrict__ x, const float* __restrict__ w1,
            const float* __restrict__ tgtdp, float* __restrict__ h1)
{
  __shared__ float As[16][132];
  __shared__ float Bs[16][68];
  int mB = blockIdx.x*128, nB = blockIdx.y*64;
  int t = threadIdx.x, tx = t & 15, ty = t >> 4;
  float acc[8][4] = {};
  for (int k0 = 0; k0 < 768; k0 += 16){
    __syncthreads();
    {
      int kc = (t & 3) * 4;
      int m0 = t >> 2;                 // 0..63
      #pragma unroll
      for (int half = 0; half < 2; ++half){
        int m = m0 + half*64;
        int row = mB + m;
        int ga = ((row >> 8) * 320) + 64 + (row & 255);   // search-token remap
        float4 av = *(const float4*)&x[(size_t)ga*768 + k0 + kc];
        As[kc+0][m] = av.x; As[kc+1][m] = av.y; As[kc+2][m] = av.z; As[kc+3][m] = av.w;
      }
      int n = t >> 2;
      float4 bv = *(const float4*)&w1[(size_t)(nB+n)*1536 + k0 + kc];
      Bs[kc+0][n] = bv.x; Bs[kc+1][n] = bv.y; Bs[kc+2][n] = bv.z; Bs[kc+3][n] = bv.w;
    }
    __syncthreads();
    #pragma unroll
    for (int k = 0; k < 16; ++k){
      float a8[8], b4[4];
      *(float4*)&a8[0] = *(const float4*)&As[k][ty*8];
      *(float4*)&a8[4] = *(const float4*)&As[k][ty*8 + 4];
      *(float4*)&b4[0] = *(const float4*)&Bs[k][tx*4];
      #pragma unroll
      for (int i = 0; i < 8; ++i)
        #pragma unroll
        for (int j = 0; j < 4; ++j)
          acc[i][j] += a8[i] * b4[j];
    }
  }
  #pragma unroll
  for (int i = 0; i < 8; ++i){
    int row = mB + ty*8 + i;
    const float* tp = &tgtdp[(row >> 8)*384];
    #pragma unroll
    for (int j = 0; j < 4; ++j){
      int n = nB + tx*4 + j;
      h1[(size_t)row*384 + n] = gelu_exact(acc[i][j] + tp[n]);
    }
  }
}

// ---------- mlp2 fp32 SGEMM 64x64 tile (decision path) ----------
__global__ __launch_bounds__(256)
void k_mlp2(const float* __restrict__ h1, const float* __restrict__ BT,
            const float* __restrict__ bias, float* __restrict__ out)
{
  __shared__ float As[16][68];
  __shared__ float Bs[16][68];
  int mB = blockIdx.x*64, nB = blockIdx.y*64;
  int t = threadIdx.x;
  int tx = t & 15, ty = t >> 4;
  float acc[4][4] = {};
  for (int k0 = 0; k0 < 384; k0 += 16){
    __syncthreads();
    {
      int m = t >> 2, kc = (t & 3) * 4;
      float4 av = *(const float4*)&h1[(size_t)(mB+m)*384 + k0 + kc];
      As[kc+0][m] = av.x; As[kc+1][m] = av.y; As[kc+2][m] = av.z; As[kc+3][m] = av.w;
      float4 bv = *(const float4*)&BT[(size_t)(nB+m)*384 + k0 + kc];
      Bs[kc+0][m] = bv.x; Bs[kc+1][m] = bv.y; Bs[kc+2][m] = bv.z; Bs[kc+3][m] = bv.w;
    }
    __syncthreads();
    #pragma unroll
    for (int k = 0; k < 16; ++k){
      float4 av = *(const float4*)&As[k][ty*4];
      float4 bv = *(const float4*)&Bs[k][tx*4];
      float a4[4] = {av.x, av.y, av.z, av.w};
      float b4[4] = {bv.x, bv.y, bv.z, bv.w};
      #pragma unroll
      for (int i = 0; i < 4; ++i)
        #pragma unroll
        for (int j = 0; j < 4; ++j)
          acc[i][j] += a4[i] * b4[j];
    }
  }
  #pragma unroll
  for (int i = 0; i < 4; ++i){
    int row = mB + ty*4 + i;
    #pragma unroll
    for (int j = 0; j < 4; ++j){
      int n = nB + tx*4 + j;
      out[(size_t)row*192 + n] = gelu_exact(acc[i][j] + bias[n]);
    }
  }
}

// ---------- decision: logits, argmax, one-hot (fp32 out), group ids ----------
__global__ void k_decide(const float* __restrict__ h2, const float* __restrict__ w3,
                         const float* __restrict__ b3, float* __restrict__ dec,
                         unsigned char* __restrict__ gid)
{
  int t = blockIdx.x*256 + threadIdx.x;   // 0..8191
  int b = t >> 8, s = t & 255;
  const float* hr = h2 + (size_t)t*192;
  float l0 = b3[0], l1 = b3[1];
  for (int c = 0; c < 192; c += 4){
    float4 h = *(const float4*)&hr[c];
    float4 wa = *(const float4*)&w3[c];
    float4 wb = *(const float4*)&w3[192 + c];
    l0 += h.x*wa.x + h.y*wa.y + h.z*wa.z + h.w*wa.w;
    l1 += h.x*wb.x + h.y*wb.y + h.z*wb.z + h.w*wb.w;
  }
  int idx = (l1 > l0) ? 1 : 0;            // jnp.argmax: first max wins
  dec[t*2 + 0] = (idx == 0) ? 1.f : 0.f;
  dec[t*2 + 1] = (idx == 1) ? 1.f : 0.f;
  gid[b*320 + 64 + s] = (unsigned char)(2 + idx);
  if (s < 64) gid[b*320 + s] = 1;         // template tokens -> group 1
}

// ---------- bf16 MFMA GEMM, 128x128 tile, BK=32, global_load_lds staging ----------
// MODE 0: qkv  — A=xb, BT=qkvwb; +bias(f32), scatter Qg/Kg ([bh][j][d]), Vg ([bh][d][j])
// MODE 1: proj — A=aout(bf16), BT=projwb; +bias -> fp32 out
template<int MODE>
__global__ __launch_bounds__(256, 2)
void k_gemm(const u16* __restrict__ A, const u16* __restrict__ BT,
            const float* __restrict__ bias, float* __restrict__ outp,
            u16* __restrict__ Qg, u16* __restrict__ Kg, u16* __restrict__ Vg)
{
  const int K = 768;
  __shared__ u16 As[128*32];   // unpadded: required by global_load_lds lane mapping
  __shared__ u16 Bs[128*32];
  int mB = blockIdx.x*128, nB = blockIdx.y*128;
  int t = threadIdx.x;
  int w = t >> 6, l = t & 63;
  int wr = w >> 1, wc = w & 1;
  int lm = l & 15, lq = l >> 4;

  f32x4 zero4 = {0.f,0.f,0.f,0.f};
  f32x4 acc[4][4];
  #pragma unroll
  for (int i = 0; i < 4; ++i)
    #pragma unroll
    for (int j = 0; j < 4; ++j) acc[i][j] = zero4;

  // per-wave staging addresses: wave w covers rows [w*32, w*32+32)
  int srow = w*32 + (l >> 2);
  int skc  = (l & 3) * 8;
  u16* baseA = As + w*1024;        // wave-uniform
  u16* baseB = Bs + w*1024;

  for (int k0 = 0; k0 < K; k0 += 32){
    __syncthreads();
    const u16* gA = A  + (size_t)(mB + srow)*768 + k0 + skc;
    const u16* gB = BT + (size_t)(nB + srow)*768 + k0 + skc;
    ASYNC16(baseA,       gA);
    ASYNC16(baseB,       gB);
    ASYNC16(baseA + 512, gA + 16*768);
    ASYNC16(baseB + 512, gB + 16*768);
    __syncthreads();   // drains vmcnt before any wave reads LDS
    short8 af[4], bfv[4];
    #pragma unroll
    for (int mt = 0; mt < 4; ++mt)
      af[mt] = *(const short8*)&As[(wr*64 + mt*16 + lm)*32 + lq*8];
    #pragma unroll
    for (int nt = 0; nt < 4; ++nt)
      bfv[nt] = *(const short8*)&Bs[(wc*64 + nt*16 + lm)*32 + lq*8];
    #pragma unroll
    for (int mt = 0; mt < 4; ++mt)
      #pragma unroll
      for (int nt = 0; nt < 4; ++nt)
        acc[mt][nt] = __builtin_amdgcn_mfma_f32_16x16x32_bf16(af[mt], bfv[nt], acc[mt][nt], 0, 0, 0);
  }

  // epilogue: C layout col=lane&15, row=(lane>>4)*4+reg
  #pragma unroll
  for (int mt = 0; mt < 4; ++mt){
    #pragma unroll
    for (int nt = 0; nt < 4; ++nt){
      int coln  = nB + wc*64 + nt*16 + lm;
      int rbase = mB + wr*64 + mt*16 + lq*4;
      float bv = bias[coln];
      if (MODE == 0){
        int bidx = rbase / 320;             // 4-row group never straddles a batch boundary
        int j = rbase - bidx*320;
        if (coln >= 1536){
          int h = (coln - 1536) >> 6, d = coln & 63;
          ushort4 pk;
          pk.x = f2bf(acc[mt][nt][0] + bv);
          pk.y = f2bf(acc[mt][nt][1] + bv);
          pk.z = f2bf(acc[mt][nt][2] + bv);
          pk.w = f2bf(acc[mt][nt][3] + bv);
          *(ushort4*)&Vg[((size_t)(bidx*12 + h)*64 + d)*320 + j] = pk;
        } else {
          bool isq = coln < 768;
          int ch = isq ? coln : (coln - 768);
          int h = ch >> 6, d = ch & 63;
          u16* dst = isq ? Qg : Kg;
          #pragma unroll
          for (int r = 0; r < 4; ++r)
            dst[((size_t)(bidx*12 + h)*320 + (j + r))*64 + d] = f2bf(acc[mt][nt][r] + bv);
        }
      } else {
        #pragma unroll
        for (int r = 0; r < 4; ++r)
          outp[(size_t)(rbase + r)*768 + coln] = acc[mt][nt][r] + bv;
      }
    }
  }
}

// ---------- attention: one block per (bh, qt) — 1920 blocks ----------
__global__ __launch_bounds__(256, 1)
void k_attn(const u16* __restrict__ Qg, const u16* __restrict__ Kg,
            const u16* __restrict__ Vg, const unsigned char* __restrict__ gid,
            u16* __restrict__ aout)
{
  __shared__ u16 Ps[64*328];     // P (C-layout -> A-layout round-trip), padded
  __shared__ float vsp[4][64];
  __shared__ float vsum[64];
  __shared__ unsigned char gls[320];
  int bh = blockIdx.x % 384;     // all 5 qt of a head land on one XCD (384 % 8 == 0)
  int qt = blockIdx.x / 384;
  int b = bh / 12, h = bh % 12;
  int t = threadIdx.x, w = t >> 6, l = t & 63;
  int lm = l & 15, lq = l >> 4;
  const u16* Ksrc = Kg + (size_t)bh*320*64;   // [j][d]
  const u16* Vsrc = Vg + (size_t)bh*64*320;   // [d][j] (transposed)
  const u16* Qsrc = Qg + (size_t)bh*320*64;   // [j][d]

  for (int c = t; c < 320; c += 256) gls[c] = gid[b*320 + c];
  {
    int d = l, p = w;
    float s = 0.f;
    const u16* vr = Vsrc + (size_t)d*320 + p*80;
    for (int j = 0; j < 80; ++j) s += bf2f(vr[j]);
    vsp[p][d] = s;
  }
  __syncthreads();
  if (t < 64) vsum[t] = (vsp[0][t] + vsp[1][t] + vsp[2][t] + vsp[3][t]) * (1e-6f/320.f);
  __syncthreads();

  f32x4 zero4 = {0.f,0.f,0.f,0.f};
  const float cexp = 0.125f * 1.44269504088896340736f;  // scale * log2(e)

  int qb = qt*64 + w*16;                 // wave's 16 q rows
  const u16* qp = Qsrc + (size_t)(qb + lm)*64 + lq*8;
  short8 qf0 = *(const short8*)qp;
  short8 qf1 = *(const short8*)(qp + 32);
  f32x4 sacc[20];
  #pragma unroll
  for (int jt = 0; jt < 20; ++jt){
    const u16* kp = Ksrc + (size_t)(jt*16 + lm)*64 + lq*8;
    short8 kf0 = *(const short8*)kp;
    short8 kf1 = *(const short8*)(kp + 32);
    f32x4 a = zero4;
    a = __builtin_amdgcn_mfma_f32_16x16x32_bf16(qf0, kf0, a, 0, 0, 0);
    a = __builtin_amdgcn_mfma_f32_16x16x32_bf16(qf1, kf1, a, 0, 0, 0);
    sacc[jt] = a;
  }
  // full-row max BEFORE masking (reference semantics)
  float mx[4];
  #pragma unroll
  for (int r = 0; r < 4; ++r){
    float m = sacc[0][r];
    #pragma unroll
    for (int jt = 1; jt < 20; ++jt) m = fmaxf(m, sacc[jt][r]);
    mx[r] = m;
  }
  #pragma unroll
  for (int off = 1; off < 16; off <<= 1)
    #pragma unroll
    for (int r = 0; r < 4; ++r)
      mx[r] = fmaxf(mx[r], __shfl_xor(mx[r], off, 64));
  int gi[4];
  #pragma unroll
  for (int r = 0; r < 4; ++r) gi[r] = gls[qb + lq*4 + r];
  float sm[4] = {0.f, 0.f, 0.f, 0.f};
  #pragma unroll
  for (int jt = 0; jt < 20; ++jt){
    int j = jt*16 + lm;
    int gj = gls[j];
    #pragma unroll
    for (int r = 0; r < 4; ++r){
      float e = exp2f((sacc[jt][r] - mx[r]) * cexp);
      if ((gi[r] != 3) && (gj != 3) && (gi[r] != gj)) e = 0.f;  // ap==0 pairs
      sm[r] += e;
      Ps[(w*16 + lq*4 + r)*328 + j] = f2bf(e);
    }
  }
  #pragma unroll
  for (int off = 1; off < 16; off <<= 1)
    #pragma unroll
    for (int r = 0; r < 4; ++r)
      sm[r] += __shfl_xor(sm[r], off, 64);
  float inv[4];
  #pragma unroll
  for (int r = 0; r < 4; ++r) inv[r] = 1.0f / (sm[r] + 1e-6f);
  __syncthreads();   // drain Ps writes before A-layout reads
  // PV: out[16,64] = P[16,320] @ V[320,64]; V^T fragments from global
  f32x4 oacc[4];
  #pragma unroll
  for (int nt = 0; nt < 4; ++nt) oacc[nt] = zero4;
  #pragma unroll
  for (int ks = 0; ks < 10; ++ks){
    short8 pf = *(const short8*)&Ps[(w*16 + lm)*328 + ks*32 + lq*8];
    #pragma unroll
    for (int nt = 0; nt < 4; ++nt){
      short8 vf = *(const short8*)&Vsrc[(size_t)(nt*16 + lm)*320 + ks*32 + lq*8];
      oacc[nt] = __builtin_amdgcn_mfma_f32_16x16x32_bf16(pf, vf, oacc[nt], 0, 0, 0);
    }
  }
  #pragma unroll
  for (int nt = 0; nt < 4; ++nt){
    int d = nt*16 + lm;
    float vs = vsum[d];
    #pragma unroll
    for (int r = 0; r < 4; ++r){
      int row = qt*64 + w*16 + lq*4 + r;
      float v = (oacc[nt][r] + vs) * inv[r];
      aout[(size_t)(b*320 + row)*768 + h*64 + d] = f2bf(v);
    }
  }
}

// ---------- launch ----------
extern "C" void kernel_launch(void* const* d_in, const int* in_sizes, int n_in,
                              void* d_out, int out_size, void* d_ws, size_t ws_size,
                              hipStream_t stream)
{
  const float* x      = (const float*)d_in[0];
  const float* tmask  = (const float*)d_in[1];
  const float* qkv_w  = (const float*)d_in[2];
  const float* qkv_b  = (const float*)d_in[3];
  const float* proj_w = (const float*)d_in[4];
  const float* proj_b = (const float*)d_in[5];
  const float* dp1_w  = (const float*)d_in[6];
  const float* dp1_b  = (const float*)d_in[7];
  const float* dp2_w  = (const float*)d_in[8];
  const float* dp2_b  = (const float*)d_in[9];
  const float* dp3_w  = (const float*)d_in[10];
  const float* dp3_b  = (const float*)d_in[11];

  char* ws = (char*)d_ws;
  float* tgtdp  = (float*)(ws + 98304);        // 32*384 f32        -> 147456
  float* h1     = (float*)(ws + 147456);       // 8192*384 f32      -> 12730368
  float* h2     = (float*)(ws + 12730368);     // 8192*192 f32      -> 19021824
  unsigned char* gid = (unsigned char*)(ws + 19021824);  // 10240   -> 19032064
  u16* xb     = (u16*)(ws + 19032064);         // 10240*768 bf16    -> 34760704
  u16* qkvwb  = (u16*)(ws + 34760704);         // 2304*768 bf16     -> 38299648
  u16* projwb = (u16*)(ws + 38299648);         // 768*768 bf16      -> 39479296
  u16* Qg     = (u16*)(ws + 39479296);         // [bh][320][64]     -> 55207936
  u16* Kg     = (u16*)(ws + 55207936);         //                   -> 70936576
  u16* Vg     = (u16*)(ws + 70936576);         // [bh][64][320]     -> 86665216
  u16* aout   = (u16*)(ws + 147456);           // bf16, overlaps dead h1/h2

  float* out = (float*)d_out;
  float* dec = out + 7864320;

  hipLaunchKernelGGL(k_cvt, dim3(7680), dim3(256), 0, stream, x, xb, 1966080);
  hipLaunchKernelGGL(k_cvt, dim3(1728), dim3(256), 0, stream, qkv_w, qkvwb, 442368);
  hipLaunchKernelGGL(k_cvt, dim3(576),  dim3(256), 0, stream, proj_w, projwb, 147456);
  hipLaunchKernelGGL(k_tgtdp, dim3(32), dim3(384), 0, stream, x, tmask, dp1_w, dp1_b, tgtdp);
  hipLaunchKernelGGL(k_mlp1,  dim3(64, 6), dim3(256), 0, stream, x, dp1_w, tgtdp, h1);
  hipLaunchKernelGGL(k_mlp2,  dim3(128, 3), dim3(256), 0, stream, h1, dp2_w, dp2_b, h2);
  hipLaunchKernelGGL(k_decide, dim3(32), dim3(256), 0, stream, h2, dp3_w, dp3_b, dec, gid);
  hipLaunchKernelGGL((k_gemm<0>), dim3(80, 18), dim3(256), 0, stream,
                     xb, qkvwb, qkv_b, (float*)nullptr, Qg, Kg, Vg);
  hipLaunchKernelGGL(k_attn,  dim3(1920), dim3(256), 0, stream, Qg, Kg, Vg, gid, aout);
  hipLaunchKernelGGL((k_gemm<1>), dim3(80, 6), dim3(256), 0, stream,
                     aout, projwb, proj_b, out, (u16*)nullptr, (u16*)nullptr, (u16*)nullptr);
}

// Round 5
// 451.176 us; speedup vs baseline: 1.0022x; 1.0022x over previous
//
#include <hip/hip_runtime.h>
#include <hip/hip_bf16.h>

typedef unsigned short u16;
typedef __attribute__((ext_vector_type(8))) short short8;
typedef __attribute__((ext_vector_type(4))) float f32x4;

// async global->LDS 16B per lane; LDS dest = wave-uniform base + lane*16
#define ASYNC16(ldsp, gp) __builtin_amdgcn_global_load_lds( \
    (const __attribute__((address_space(1))) unsigned int*)(gp), \
    (__attribute__((address_space(3))) unsigned int*)(ldsp), 16, 0, 0)

// ---------- helpers ----------
__device__ __forceinline__ float bf2f(u16 u){
  union { unsigned int i; float f; } v; v.i = ((unsigned int)u) << 16; return v.f;
}
__device__ __forceinline__ u16 f2bf(float f){
  union { float f; unsigned int i; } v; v.f = f;
  unsigned int x = v.i;
  return (u16)((x + 0x7fffu + ((x >> 16) & 1u)) >> 16);
}
__device__ __forceinline__ float gelu_exact(float x){
  return 0.5f * x * (1.0f + erff(x * 0.70710678118654752440f));
}

// B=32 N=320 C=768 H=12 S=256 T=64 hd=64; ALL I/O fp32.

// ---------- convert fp32 -> bf16 ----------
__global__ void k_cvt(const float* __restrict__ src, u16* __restrict__ dst, int n4){
  int i = blockIdx.x*256 + threadIdx.x;
  if (i < n4){
    float4 v = ((const float4*)src)[i];
    ushort4 p; p.x = f2bf(v.x); p.y = f2bf(v.y); p.z = f2bf(v.z); p.w = f2bf(v.w);
    ((ushort4*)dst)[i] = p;
  }
}

// ---------- fused: tgt_rep mean-pool + tgt-half of dp1 (per batch) ----------
// phase 2: wave per 64 outputs, lanes sweep c (coalesced), shuffle-reduce.
__global__ __launch_bounds__(384)
void k_tgtdp(const float* __restrict__ x, const float* __restrict__ tmask,
             const float* __restrict__ w1, const float* __restrict__ b1,
             float* __restrict__ tgtdp){
  __shared__ float tg[768];
  __shared__ float msk[64];
  int b = blockIdx.x;
  int t = threadIdx.x;   // 384 = 6 waves
  if (t < 64) msk[t] = tmask[b*64 + t];
  __syncthreads();
  for (int c = t; c < 768; c += 384){
    float s = 0.f;
    for (int tt = 0; tt < 64; ++tt)
      s += x[(size_t)(b*320 + tt)*768 + c] * msk[tt];
    tg[c] = s * (1.0f/64.0f);
  }
  __syncthreads();
  int w = t >> 6, l = t & 63;
  for (int oi = 0; oi < 64; ++oi){
    int o = w*64 + oi;
    const float* wr = w1 + (size_t)o*1536 + 768;
    float s = 0.f;
    #pragma unroll
    for (int ci = 0; ci < 12; ++ci){
      int c = ci*64 + l;
      s += tg[c] * wr[c];
    }
    #pragma unroll
    for (int off = 1; off < 64; off <<= 1) s += __shfl_xor(s, off, 64);
    if (l == 0) tgtdp[b*384 + o] = s + b1[o];
  }
}

// ---------- mlp1 fp32 SGEMM 128x64 tile, 8x4 per thread (decision path) ----------
__global__ __launch_bounds__(256)
void k_mlp1(const float* __restrict__ x, const float* __restrict__ w1,
            const float* __restrict__ tgtdp, float* __restrict__ h1)
{
  __shared__ float As[16][132];
  __shared__ float Bs[16][68];
  int mB = blockIdx.x*128, nB = blockIdx.y*64;
  int t = threadIdx.x, tx = t & 15, ty = t >> 4;
  float acc[8][4] = {};
  for (int k0 = 0; k0 < 768; k0 += 16){
    __syncthreads();
    {
      int kc = (t & 3) * 4;
      int m0 = t >> 2;                 // 0..63
      #pragma unroll
      for (int half = 0; half < 2; ++half){
        int m = m0 + half*64;
        int row = mB + m;
        int ga = ((row >> 8) * 320) + 64 + (row & 255);   // search-token remap
        float4 av = *(const float4*)&x[(size_t)ga*768 + k0 + kc];
        As[kc+0][m] = av.x; As[kc+1][m] = av.y; As[kc+2][m] = av.z; As[kc+3][m] = av.w;
      }
      int n = t >> 2;
      float4 bv = *(const float4*)&w1[(size_t)(nB+n)*1536 + k0 + kc];
      Bs[kc+0][n] = bv.x; Bs[kc+1][n] = bv.y; Bs[kc+2][n] = bv.z; Bs[kc+3][n] = bv.w;
    }
    __syncthreads();
    #pragma unroll
    for (int k = 0; k < 16; ++k){
      float a8[8], b4[4];
      *(float4*)&a8[0] = *(const float4*)&As[k][ty*8];
      *(float4*)&a8[4] = *(const float4*)&As[k][ty*8 + 4];
      *(float4*)&b4[0] = *(const float4*)&Bs[k][tx*4];
      #pragma unroll
      for (int i = 0; i < 8; ++i)
        #pragma unroll
        for (int j = 0; j < 4; ++j)
          acc[i][j] += a8[i] * b4[j];
    }
  }
  #pragma unroll
  for (int i = 0; i < 8; ++i){
    int row = mB + ty*8 + i;
    const float* tp = &tgtdp[(row >> 8)*384];
    #pragma unroll
    for (int j = 0; j < 4; ++j){
      int n = nB + tx*4 + j;
      h1[(size_t)row*384 + n] = gelu_exact(acc[i][j] + tp[n]);
    }
  }
}

// ---------- mlp2 fp32 SGEMM 64x64 tile (decision path) ----------
__global__ __launch_bounds__(256)
void k_mlp2(const float* __restrict__ h1, const float* __restrict__ BT,
            const float* __restrict__ bias, float* __restrict__ out)
{
  __shared__ float As[16][68];
  __shared__ float Bs[16][68];
  int mB = blockIdx.x*64, nB = blockIdx.y*64;
  int t = threadIdx.x;
  int tx = t & 15, ty = t >> 4;
  float acc[4][4] = {};
  for (int k0 = 0; k0 < 384; k0 += 16){
    __syncthreads();
    {
      int m = t >> 2, kc = (t & 3) * 4;
      float4 av = *(const float4*)&h1[(size_t)(mB+m)*384 + k0 + kc];
      As[kc+0][m] = av.x; As[kc+1][m] = av.y; As[kc+2][m] = av.z; As[kc+3][m] = av.w;
      float4 bv = *(const float4*)&BT[(size_t)(nB+m)*384 + k0 + kc];
      Bs[kc+0][m] = bv.x; Bs[kc+1][m] = bv.y; Bs[kc+2][m] = bv.z; Bs[kc+3][m] = bv.w;
    }
    __syncthreads();
    #pragma unroll
    for (int k = 0; k < 16; ++k){
      float4 av = *(const float4*)&As[k][ty*4];
      float4 bv = *(const float4*)&Bs[k][tx*4];
      float a4[4] = {av.x, av.y, av.z, av.w};
      float b4[4] = {bv.x, bv.y, bv.z, bv.w};
      #pragma unroll
      for (int i = 0; i < 4; ++i)
        #pragma unroll
        for (int j = 0; j < 4; ++j)
          acc[i][j] += a4[i] * b4[j];
    }
  }
  #pragma unroll
  for (int i = 0; i < 4; ++i){
    int row = mB + ty*4 + i;
    #pragma unroll
    for (int j = 0; j < 4; ++j){
      int n = nB + tx*4 + j;
      out[(size_t)row*192 + n] = gelu_exact(acc[i][j] + bias[n]);
    }
  }
}

// ---------- decision: 4 lanes per token ----------
__global__ void k_decide(const float* __restrict__ h2, const float* __restrict__ w3,
                         const float* __restrict__ b3, float* __restrict__ dec,
                         unsigned char* __restrict__ gid)
{
  int g = blockIdx.x*256 + threadIdx.x;   // 32768 threads
  int tok = g >> 2, q = g & 3;
  int b = tok >> 8, s = tok & 255;
  const float* hr = h2 + (size_t)tok*192 + q*48;
  const float* wa = w3 + q*48;
  const float* wb = w3 + 192 + q*48;
  float l0 = 0.f, l1 = 0.f;
  #pragma unroll
  for (int c = 0; c < 48; c += 4){
    float4 h = *(const float4*)&hr[c];
    float4 a = *(const float4*)&wa[c];
    float4 bb = *(const float4*)&wb[c];
    l0 += h.x*a.x + h.y*a.y + h.z*a.z + h.w*a.w;
    l1 += h.x*bb.x + h.y*bb.y + h.z*bb.z + h.w*bb.w;
  }
  l0 += __shfl_xor(l0, 1, 64); l0 += __shfl_xor(l0, 2, 64);
  l1 += __shfl_xor(l1, 1, 64); l1 += __shfl_xor(l1, 2, 64);
  if (q == 0){
    l0 += b3[0]; l1 += b3[1];
    int idx = (l1 > l0) ? 1 : 0;          // jnp.argmax: first max wins
    dec[tok*2 + 0] = (idx == 0) ? 1.f : 0.f;
    dec[tok*2 + 1] = (idx == 1) ? 1.f : 0.f;
    gid[b*320 + 64 + s] = (unsigned char)(2 + idx);
    if (s < 64) gid[b*320 + s] = 1;       // template tokens -> group 1
  }
}

// ---------- bf16 MFMA GEMM, 128x128 tile, BK=32, global_load_lds staging ----------
template<int MODE>
__global__ __launch_bounds__(256, 2)
void k_gemm(const u16* __restrict__ A, const u16* __restrict__ BT,
            const float* __restrict__ bias, float* __restrict__ outp,
            u16* __restrict__ Qg, u16* __restrict__ Kg, u16* __restrict__ Vg)
{
  const int K = 768;
  __shared__ u16 As[128*32];   // unpadded: required by global_load_lds lane mapping
  __shared__ u16 Bs[128*32];
  int mB = blockIdx.x*128, nB = blockIdx.y*128;
  int t = threadIdx.x;
  int w = t >> 6, l = t & 63;
  int wr = w >> 1, wc = w & 1;
  int lm = l & 15, lq = l >> 4;

  f32x4 zero4 = {0.f,0.f,0.f,0.f};
  f32x4 acc[4][4];
  #pragma unroll
  for (int i = 0; i < 4; ++i)
    #pragma unroll
    for (int j = 0; j < 4; ++j) acc[i][j] = zero4;

  int srow = w*32 + (l >> 2);
  int skc  = (l & 3) * 8;
  u16* baseA = As + w*1024;        // wave-uniform
  u16* baseB = Bs + w*1024;

  for (int k0 = 0; k0 < K; k0 += 32){
    __syncthreads();
    const u16* gA = A  + (size_t)(mB + srow)*768 + k0 + skc;
    const u16* gB = BT + (size_t)(nB + srow)*768 + k0 + skc;
    ASYNC16(baseA,       gA);
    ASYNC16(baseB,       gB);
    ASYNC16(baseA + 512, gA + 16*768);
    ASYNC16(baseB + 512, gB + 16*768);
    __syncthreads();
    short8 af[4], bfv[4];
    #pragma unroll
    for (int mt = 0; mt < 4; ++mt)
      af[mt] = *(const short8*)&As[(wr*64 + mt*16 + lm)*32 + lq*8];
    #pragma unroll
    for (int nt = 0; nt < 4; ++nt)
      bfv[nt] = *(const short8*)&Bs[(wc*64 + nt*16 + lm)*32 + lq*8];
    #pragma unroll
    for (int mt = 0; mt < 4; ++mt)
      #pragma unroll
      for (int nt = 0; nt < 4; ++nt)
        acc[mt][nt] = __builtin_amdgcn_mfma_f32_16x16x32_bf16(af[mt], bfv[nt], acc[mt][nt], 0, 0, 0);
  }

  // epilogue: C layout col=lane&15, row=(lane>>4)*4+reg
  #pragma unroll
  for (int mt = 0; mt < 4; ++mt){
    #pragma unroll
    for (int nt = 0; nt < 4; ++nt){
      int coln  = nB + wc*64 + nt*16 + lm;
      int rbase = mB + wr*64 + mt*16 + lq*4;
      float bv = bias[coln];
      if (MODE == 0){
        int bidx = rbase / 320;
        int j = rbase - bidx*320;
        if (coln >= 1536){
          int h = (coln - 1536) >> 6, d = coln & 63;
          ushort4 pk;
          pk.x = f2bf(acc[mt][nt][0] + bv);
          pk.y = f2bf(acc[mt][nt][1] + bv);
          pk.z = f2bf(acc[mt][nt][2] + bv);
          pk.w = f2bf(acc[mt][nt][3] + bv);
          *(ushort4*)&Vg[((size_t)(bidx*12 + h)*64 + d)*320 + j] = pk;
        } else {
          bool isq = coln < 768;
          int ch = isq ? coln : (coln - 768);
          int h = ch >> 6, d = ch & 63;
          u16* dst = isq ? Qg : Kg;
          #pragma unroll
          for (int r = 0; r < 4; ++r)
            dst[((size_t)(bidx*12 + h)*320 + (j + r))*64 + d] = f2bf(acc[mt][nt][r] + bv);
        }
      } else {
        #pragma unroll
        for (int r = 0; r < 4; ++r)
          outp[(size_t)(rbase + r)*768 + coln] = acc[mt][nt][r] + bv;
      }
    }
  }
}

// ---------- vsum[bh][d] = (eps/320) * sum_j V[bh][d][j], coalesced ----------
__global__ void k_vsum(const u16* __restrict__ Vg, float* __restrict__ vsumg){
  int bh = blockIdx.x;                 // 384
  int t = threadIdx.x;                 // 256
  int l = t & 63, w = t >> 6;
  int d = w*16 + (l >> 2);
  int c = l & 3;
  const u16* vr = Vg + (size_t)bh*64*320 + (size_t)d*320;
  float s = 0.f;
  for (int it = 0; it < 10; ++it){
    const u16* p = vr + (it*4 + c)*8;
    uint4 pk = *(const uint4*)p;
    const u16* e = (const u16*)&pk;
    #pragma unroll
    for (int i = 0; i < 8; ++i) s += bf2f(e[i]);
  }
  s += __shfl_xor(s, 1, 64);
  s += __shfl_xor(s, 2, 64);
  if (c == 0) vsumg[bh*64 + d] = s * (1e-6f/320.f);
}

// ---------- attention: one block per (bh, qt) — 1920 blocks ----------
__global__ __launch_bounds__(256, 2)
void k_attn(const u16* __restrict__ Qg, const u16* __restrict__ Kg,
            const u16* __restrict__ Vg, const unsigned char* __restrict__ gid,
            const float* __restrict__ vsumg, u16* __restrict__ aout)
{
  __shared__ u16 Ps[64*328];     // P (C-layout -> A-layout round-trip), padded
  __shared__ float vsum[64];
  __shared__ unsigned char gls[320];
  int bh = blockIdx.x % 384;     // all 5 qt of a head land on one XCD (384 % 8 == 0)
  int qt = blockIdx.x / 384;
  int b = bh / 12, h = bh % 12;
  int t = threadIdx.x, w = t >> 6, l = t & 63;
  int lm = l & 15, lq = l >> 4;
  const u16* Ksrc = Kg + (size_t)bh*320*64;   // [j][d]
  const u16* Vsrc = Vg + (size_t)bh*64*320;   // [d][j] (transposed)
  const u16* Qsrc = Qg + (size_t)bh*320*64;   // [j][d]

  for (int c = t; c < 320; c += 256) gls[c] = gid[b*320 + c];
  if (t < 64) vsum[t] = vsumg[bh*64 + t];
  __syncthreads();

  f32x4 zero4 = {0.f,0.f,0.f,0.f};
  const float cexp = 0.125f * 1.44269504088896340736f;  // scale * log2(e)

  int qb = qt*64 + w*16;                 // wave's 16 q rows
  const u16* qp = Qsrc + (size_t)(qb + lm)*64 + lq*8;
  short8 qf0 = *(const short8*)qp;
  short8 qf1 = *(const short8*)(qp + 32);
  f32x4 sacc[20];
  #pragma unroll
  for (int jt = 0; jt < 20; ++jt){
    const u16* kp = Ksrc + (size_t)(jt*16 + lm)*64 + lq*8;
    short8 kf0 = *(const short8*)kp;
    short8 kf1 = *(const short8*)(kp + 32);
    f32x4 a = zero4;
    a = __builtin_amdgcn_mfma_f32_16x16x32_bf16(qf0, kf0, a, 0, 0, 0);
    a = __builtin_amdgcn_mfma_f32_16x16x32_bf16(qf1, kf1, a, 0, 0, 0);
    sacc[jt] = a;
  }
  // full-row max BEFORE masking (reference semantics)
  float mx[4];
  #pragma unroll
  for (int r = 0; r < 4; ++r){
    float m = sacc[0][r];
    #pragma unroll
    for (int jt = 1; jt < 20; ++jt) m = fmaxf(m, sacc[jt][r]);
    mx[r] = m;
  }
  #pragma unroll
  for (int off = 1; off < 16; off <<= 1)
    #pragma unroll
    for (int r = 0; r < 4; ++r)
      mx[r] = fmaxf(mx[r], __shfl_xor(mx[r], off, 64));
  int gi[4];
  #pragma unroll
  for (int r = 0; r < 4; ++r) gi[r] = gls[qb + lq*4 + r];
  float sm[4] = {0.f, 0.f, 0.f, 0.f};
  #pragma unroll
  for (int jt = 0; jt < 20; ++jt){
    int j = jt*16 + lm;
    int gj = gls[j];
    #pragma unroll
    for (int r = 0; r < 4; ++r){
      float e = exp2f((sacc[jt][r] - mx[r]) * cexp);
      if ((gi[r] != 3) && (gj != 3) && (gi[r] != gj)) e = 0.f;  // ap==0 pairs
      sm[r] += e;
      Ps[(w*16 + lq*4 + r)*328 + j] = f2bf(e);
    }
  }
  #pragma unroll
  for (int off = 1; off < 16; off <<= 1)
    #pragma unroll
    for (int r = 0; r < 4; ++r)
      sm[r] += __shfl_xor(sm[r], off, 64);
  float inv[4];
  #pragma unroll
  for (int r = 0; r < 4; ++r) inv[r] = 1.0f / (sm[r] + 1e-6f);
  __syncthreads();   // drain Ps writes before A-layout reads
  // PV: out[16,64] = P[16,320] @ V[320,64]; V^T fragments from global
  f32x4 oacc[4];
  #pragma unroll
  for (int nt = 0; nt < 4; ++nt) oacc[nt] = zero4;
  #pragma unroll
  for (int ks = 0; ks < 10; ++ks){
    short8 pf = *(const short8*)&Ps[(w*16 + lm)*328 + ks*32 + lq*8];
    #pragma unroll
    for (int nt = 0; nt < 4; ++nt){
      short8 vf = *(const short8*)&Vsrc[(size_t)(nt*16 + lm)*320 + ks*32 + lq*8];
      oacc[nt] = __builtin_amdgcn_mfma_f32_16x16x32_bf16(pf, vf, oacc[nt], 0, 0, 0);
    }
  }
  #pragma unroll
  for (int nt = 0; nt < 4; ++nt){
    int d = nt*16 + lm;
    float vs = vsum[d];
    #pragma unroll
    for (int r = 0; r < 4; ++r){
      int row = qt*64 + w*16 + lq*4 + r;
      float v = (oacc[nt][r] + vs) * inv[r];
      aout[(size_t)(b*320 + row)*768 + h*64 + d] = f2bf(v);
    }
  }
}

// ---------- launch ----------
extern "C" void kernel_launch(void* const* d_in, const int* in_sizes, int n_in,
                              void* d_out, int out_size, void* d_ws, size_t ws_size,
                              hipStream_t stream)
{
  const float* x      = (const float*)d_in[0];
  const float* tmask  = (const float*)d_in[1];
  const float* qkv_w  = (const float*)d_in[2];
  const float* qkv_b  = (const float*)d_in[3];
  const float* proj_w = (const float*)d_in[4];
  const float* proj_b = (const float*)d_in[5];
  const float* dp1_w  = (const float*)d_in[6];
  const float* dp1_b  = (const float*)d_in[7];
  const float* dp2_w  = (const float*)d_in[8];
  const float* dp2_b  = (const float*)d_in[9];
  const float* dp3_w  = (const float*)d_in[10];
  const float* dp3_b  = (const float*)d_in[11];

  char* ws = (char*)d_ws;
  float* tgtdp  = (float*)(ws + 0);            // 32*384 f32        -> 49152
  float* vsumg  = (float*)(ws + 49152);        // 384*64 f32        -> 147456
  float* h1     = (float*)(ws + 147456);       // 8192*384 f32      -> 12730368
  float* h2     = (float*)(ws + 12730368);     // 8192*192 f32      -> 19021824
  unsigned char* gid = (unsigned char*)(ws + 19021824);  // 10240   -> 19032064
  u16* xb     = (u16*)(ws + 19032064);         // 10240*768 bf16    -> 34760704
  u16* qkvwb  = (u16*)(ws + 34760704);         // 2304*768 bf16     -> 38299648
  u16* projwb = (u16*)(ws + 38299648);         // 768*768 bf16      -> 39479296
  u16* Qg     = (u16*)(ws + 39479296);         // [bh][320][64]     -> 55207936
  u16* Kg     = (u16*)(ws + 55207936);         //                   -> 70936576
  u16* Vg     = (u16*)(ws + 70936576);         // [bh][64][320]     -> 86665216
  u16* aout   = (u16*)(ws + 147456);           // bf16, overlaps dead h1/h2

  float* out = (float*)d_out;
  float* dec = out + 7864320;

  hipLaunchKernelGGL(k_cvt, dim3(7680), dim3(256), 0, stream, x, xb, 1966080);
  hipLaunchKernelGGL(k_cvt, dim3(1728), dim3(256), 0, stream, qkv_w, qkvwb, 442368);
  hipLaunchKernelGGL(k_cvt, dim3(576),  dim3(256), 0, stream, proj_w, projwb, 147456);
  hipLaunchKernelGGL(k_tgtdp, dim3(32), dim3(384), 0, stream, x, tmask, dp1_w, dp1_b, tgtdp);
  hipLaunchKernelGGL(k_mlp1,  dim3(64, 6), dim3(256), 0, stream, x, dp1_w, tgtdp, h1);
  hipLaunchKernelGGL(k_mlp2,  dim3(128, 3), dim3(256), 0, stream, h1, dp2_w, dp2_b, h2);
  hipLaunchKernelGGL(k_decide, dim3(128), dim3(256), 0, stream, h2, dp3_w, dp3_b, dec, gid);
  hipLaunchKernelGGL((k_gemm<0>), dim3(80, 18), dim3(256), 0, stream,
                     xb, qkvwb, qkv_b, (float*)nullptr, Qg, Kg, Vg);
  hipLaunchKernelGGL(k_vsum, dim3(384), dim3(256), 0, stream, Vg, vsumg);
  hipLaunchKernelGGL(k_attn,  dim3(1920), dim3(256), 0, stream, Qg, Kg, Vg, gid, vsumg, aout);
  hipLaunchKernelGGL((k_gemm<1>), dim3(80, 6), dim3(256), 0, stream,
                     aout, projwb, proj_b, out, (u16*)nullptr, (u16*)nullptr, (u16*)nullptr);
}